// Round 18
// baseline (111.075 us; speedup 1.0000x reference)
//
#include <hip/hip_runtime.h>

#define NSEQ 2048
#define KDIM 1024
#define DH   64
#define NS   8
#define NR   2

typedef short bf16x8 __attribute__((ext_vector_type(8)));
typedef float f32x4  __attribute__((ext_vector_type(4)));

typedef unsigned short ushort_ma __attribute__((may_alias));
typedef bf16x8         bf16x8_ma __attribute__((may_alias));
typedef uint4          uint4_ma  __attribute__((may_alias));
typedef uint2          uint2_ma  __attribute__((may_alias));
typedef float4         float4_ma __attribute__((may_alias));

__device__ __forceinline__ unsigned short f2bf(float f) {
    unsigned int u = __builtin_bit_cast(unsigned int, f);
    u = (u + 0x7FFFu + ((u >> 16) & 1u)) >> 16;   // RTN-even
    return (unsigned short)u;
}
__device__ __forceinline__ float bf2f(unsigned short h) {
    unsigned int u = ((unsigned int)h) << 16;
    return __builtin_bit_cast(float, u);
}
__device__ __forceinline__ unsigned int cvt_pk_bf16(float lo, float hi) {
    unsigned int r;
    asm("v_cvt_pk_bf16_f32 %0, %1, %2" : "=v"(r) : "v"(lo), "v"(hi));
    return r;
}
// raw v_exp_f32 (no denormal-guard sequence); inputs here are in [-30, +8]
__device__ __forceinline__ float exp2_raw(float x) {
    return __builtin_amdgcn_exp2f(x);
}
// async global->LDS, 16B/lane. LDS dest = wave-uniform base + lane*16 (m104).
__device__ __forceinline__ void gld_lds16(void* lptr, const void* gptr) {
    __builtin_amdgcn_global_load_lds(
        (const __attribute__((address_space(1))) unsigned int*)gptr,
        (__attribute__((address_space(3))) unsigned int*)lptr, 16, 0, 0);
}

// ============ prep (merged): weights transpose + Wc + x->bf16 ============
// blocks [0,544): Wt/Wot transpose; [544,672): Wc = Wrq_s @ Wrk^T; [672,2720): x->bf16.
__global__ __launch_bounds__(256) void prep_all_k(
    const float* __restrict__ Wsq, const float* __restrict__ Wsk,
    const float* __restrict__ Wrq, const float* __restrict__ Wrv,
    const float* __restrict__ Wout, const float* __restrict__ Wrk,
    const float* __restrict__ x,
    unsigned short* __restrict__ Wt, unsigned short* __restrict__ Wot,
    unsigned short* __restrict__ xh)
{
    __shared__ float sBuf[2][64][65];
    const int tid = threadIdx.x;
    const int bid = blockIdx.x;

    if (bid >= 672) {
        // ---- x -> bf16 (single plane; x-rounding ~0.1-0.2% rel, in budget) ----
        const int total = 4096 * KDIM / 4;
        int idx = (bid - 672) * 256 + tid;
        for (int i = idx; i < total; i += 2048 * 256) {
            float4 v = ((const float4_ma*)x)[i];
            ushort4 h;
            h.x = f2bf(v.x); h.y = f2bf(v.y); h.z = f2bf(v.z); h.w = f2bf(v.w);
            ((ushort4*)xh)[i] = h;
        }
        return;
    }

    if (bid >= 544) {
        // ---- Wc_s = Wrq[:, s*64:+64] @ Wrk^T -> Wt rows [1024+s*64, +64) ----
        const int r = bid - 544;
        const int s = r & 7;
        const int k0 = (r >> 3) * 64;
        float (*sQ)[65] = sBuf[0];
        float (*sK)[65] = sBuf[1];
#pragma unroll
        for (int p = 0; p < 4; ++p) {
            int row = (tid >> 4) + p * 16;
            int col = (tid & 15) * 4;
            float4 w = *(const float4*)&Wrk[(size_t)row * 64 + col];
            sK[row][col + 0] = w.x; sK[row][col + 1] = w.y;
            sK[row][col + 2] = w.z; sK[row][col + 3] = w.w;
            float4 q = *(const float4*)&Wrq[(size_t)(k0 + row) * 512 + s * 64 + col];
            sQ[row][col + 0] = q.x; sQ[row][col + 1] = q.y;
            sQ[row][col + 2] = q.z; sQ[row][col + 3] = q.w;
        }
        __syncthreads();

        const int dd = tid >> 2;
        const int kq = (tid & 3) * 16;
        float acc[16];
#pragma unroll
        for (int j = 0; j < 16; ++j) acc[j] = 0.f;
        for (int e = 0; e < 64; ++e) {
            float w = sK[dd][e];
#pragma unroll
            for (int j = 0; j < 16; ++j) acc[j] += w * sQ[kq + j][e];
        }
        const float SC = 0.125f * 1.44269504089f;
        unsigned int w8[8];
#pragma unroll
        for (int j = 0; j < 8; ++j)
            w8[j] = (unsigned)f2bf(acc[2 * j] * SC) | ((unsigned)f2bf(acc[2 * j + 1] * SC) << 16);
        unsigned short* o = Wt + (size_t)(1024 + s * 64 + dd) * KDIM + k0 + kq;
        *(uint4_ma*)o       = make_uint4(w8[0], w8[1], w8[2], w8[3]);
        *(uint4_ma*)(o + 8) = make_uint4(w8[4], w8[5], w8[6], w8[7]);
        return;
    }

    // ---- weight transpose + f32->bf16 ----
    {
        const float* src; int ldw, k0, n0, scol, ldo;
        unsigned short* dst;
        float sc = 1.0f;
        if (bid < 416) {
            int kt = bid / 26, nt = bid % 26;
            k0 = kt * 64; n0 = nt * 64;
            if (n0 >= 1024 && n0 < 1536) return;   // Wc section handled above
            if (n0 < 512)       { src = Wsq; ldw = 512; scol = n0;        sc = 0.125f * 1.44269504089f; }
            else if (n0 < 1024) { src = Wsk; ldw = 512; scol = n0 - 512;  }
            else                { src = Wrv; ldw = 128; scol = n0 - 1536; }
            dst = Wt; ldo = KDIM;
        } else {
            int r = bid - 416;
            int kt = r >> 4, nt = r & 15;
            k0 = kt * 64; n0 = nt * 64; scol = n0;
            src = Wout; ldw = KDIM;
            dst = Wot; ldo = 512;
        }
        float (*sT)[65] = sBuf[0];
#pragma unroll
        for (int p = 0; p < 4; ++p) {
            int row = (tid >> 4) + p * 16;
            int col = (tid & 15) * 4;
            float4 v = *(const float4*)&src[(size_t)(k0 + row) * ldw + scol + col];
            sT[row][col + 0] = v.x; sT[row][col + 1] = v.y;
            sT[row][col + 2] = v.z; sT[row][col + 3] = v.w;
        }
        __syncthreads();

        int n_l = tid >> 2, kg = (tid & 3) * 16;
        unsigned int w[8];
#pragma unroll
        for (int j = 0; j < 8; ++j) {
            unsigned short a = f2bf(sT[kg + 2 * j][n_l] * sc);
            unsigned short b = f2bf(sT[kg + 2 * j + 1][n_l] * sc);
            w[j] = (unsigned)a | ((unsigned)b << 16);
        }
        unsigned short* o = dst + (size_t)(n0 + n_l) * ldo + k0 + kg;
        *(uint4_ma*)o       = make_uint4(w[0], w[1], w[2], w[3]);
        *(uint4_ma*)(o + 8) = make_uint4(w[4], w[5], w[6], w[7]);
    }
}

// ============ Kernel 1: projection GEMM (bf16 MFMA, BN=128, single-x) ============
__global__ __launch_bounds__(256) void proj_mfma_k(
    const unsigned short* __restrict__ xh,
    const unsigned short* __restrict__ Wt,
    unsigned short* __restrict__ Qb, unsigned short* __restrict__ Kf,
    float* __restrict__ RU, unsigned short* __restrict__ Vf)
{
    __shared__ __align__(16) char smem[32768];
    const int tid = threadIdx.x;
    const int bn = blockIdx.x, bm = blockIdx.y;   // bn 0..12
    const int wid = tid >> 6, lane = tid & 63;
    const int wm = wid >> 1, wn = wid & 1;
    const int lrow = lane & 15, lgrp = lane >> 4;
    const int lr = lane >> 3, lc = lane & 7;

    f32x4 acc[4][4];
#pragma unroll
    for (int i = 0; i < 4; ++i)
#pragma unroll
        for (int j = 0; j < 4; ++j) acc[i][j] = (f32x4){0.f, 0.f, 0.f, 0.f};

    for (int kt = 0; kt < KDIM / 64; ++kt) {
        __syncthreads();
#pragma unroll
        for (int i = 0; i < 4; ++i) {
            int seg = wid * 4 + i;
            int r = seg * 8 + lr;
            gld_lds16(smem + seg * 1024,
                      xh + (size_t)(bm * 128 + r) * KDIM + kt * 64 + (lc ^ (r & 7)) * 8);
            gld_lds16(smem + 16384 + seg * 1024,
                      Wt + (size_t)(bn * 128 + r) * KDIM + kt * 64 + (lc ^ (r & 7)) * 8);
        }
        __syncthreads();
#pragma unroll
        for (int ks = 0; ks < 2; ++ks) {
            bf16x8 bfr[4];
#pragma unroll
            for (int nf = 0; nf < 4; ++nf) {
                int rb = wn * 64 + nf * 16 + lrow;
                bfr[nf] = *(bf16x8_ma*)(smem + 16384 + ((rb * 128 + ks * 64 + lgrp * 16) ^ ((rb & 7) << 4)));
            }
#pragma unroll
            for (int mf = 0; mf < 4; ++mf) {
                int ra = wm * 64 + mf * 16 + lrow;
                bf16x8 ah = *(bf16x8_ma*)(smem + ((ra * 128 + ks * 64 + lgrp * 16) ^ ((ra & 7) << 4)));
#pragma unroll
                for (int nf = 0; nf < 4; ++nf)
                    acc[mf][nf] = __builtin_amdgcn_mfma_f32_16x16x32_bf16(ah, bfr[nf], acc[mf][nf], 0, 0, 0);
            }
        }
    }

    const int g = bn >> 2;   // bn 0-3:Q 4-7:K 8-11:U 12:V
#pragma unroll
    for (int mf = 0; mf < 4; ++mf) {
#pragma unroll
        for (int nf = 0; nf < 4; ++nf) {
            int j0 = bn * 128 + wn * 64 + nf * 16 + lrow;
            int m0 = bm * 128 + wm * 64 + mf * 16 + lgrp * 4;
            if (g == 3) {
                int dv = j0 - 1536;
                int bb = m0 >> 11, seq = m0 & (NSEQ - 1);
                size_t addr = (size_t)bb * 262144 + (size_t)(seq >> 6) * 8192
                    + (size_t)(((dv >> 4) * 2 + ((seq >> 5) & 1)) * 512)
                    + (((seq >> 3) & 3) * 16 + (dv & 15)) * 8 + (seq & 7);
                ushort4 h;
                h.x = f2bf(acc[mf][nf][0]); h.y = f2bf(acc[mf][nf][1]);
                h.z = f2bf(acc[mf][nf][2]); h.w = f2bf(acc[mf][nf][3]);
                *(ushort4*)&Vf[addr] = h;
            } else if (g == 1) {
                int s = (j0 >> 6) & 7, d = j0 & 63;
#pragma unroll
                for (int r = 0; r < 4; ++r) {
                    int m = m0 + r;
                    int bb = m >> 11, seq = m & (NSEQ - 1);
                    size_t base = ((size_t)(bb * NS + s)) * (NSEQ * DH)
                        + (size_t)(seq >> 6) * 4096
                        + ((((seq >> 4) & 3) * 2 + (d >> 5)) * 64
                           + ((d & 31) >> 3) * 16 + (seq & 15)) * 8 + (d & 7);
                    Kf[base] = f2bf(acc[mf][nf][r]);
                }
            } else {
                int s = (j0 >> 6) & 7, d = j0 & 63;
#pragma unroll
                for (int r = 0; r < 4; ++r) {
                    int m = m0 + r;
                    int bb = m >> 11, seq = m & (NSEQ - 1);
                    size_t idx = (((size_t)(bb * NS + s)) * NSEQ + seq) * DH + d;
                    if (g == 2) RU[idx] = acc[mf][nf][r];
                    else        Qb[idx] = f2bf(acc[mf][nf][r]);
                }
            }
        }
    }
}

// ============ Kernel 2: barrier-free fragment-direct attention, V reg-dbuf ============
// R17 + NAMED V double-buffer (vfA/vfB, loop unrolled x2): tile t+1's V loads are
// issued a FULL iteration before consumption into the buffer NOT read this iter,
// so the compiler cannot sink them to just-before-PV (R17's VGPR=92 showed it had
// sunk vf loads, exposing raw L2 latency per PV fragment). Tail over-reads land in
// adjacent workspace slots (valid memory, values unused).
__global__ __launch_bounds__(256) void attn_mfma_k(
    const unsigned short* __restrict__ Qb, const unsigned short* __restrict__ Kfr,
    const unsigned short* __restrict__ Vfr, const float* __restrict__ RU,
    unsigned short* __restrict__ O1b)
{
    __shared__ __align__(16) char smem[8192];
    const int tid = threadIdx.x;
    const int gblk = blockIdx.x;
    const int orig = ((gblk & 7) << 6) + (gblk >> 3);   // XCD-contiguous remap
    const int qt = orig & 31, s = (orig >> 5) & 7, b = orig >> 8;
    const int wid = tid >> 6, lane = tid & 63;
    const int lrow = lane & 15, lgrp = lane >> 4;

    const unsigned short* Qg = Qb + (((size_t)(b * NS + s)) * NSEQ + qt * 64) * DH;
    const unsigned short* kp0 = Kfr + ((size_t)(b * NS + s)) * (NSEQ * DH) + lane * 8;
    const unsigned short* kp1 = kp0 + 2048;
    const unsigned short* vp0 = Vfr + (size_t)b * 262144 + lane * 8;
    const unsigned short* vp1 = vp0 + 2048;
    const unsigned short* vp2 = vp0 + 4096;
    const unsigned short* vp3 = vp0 + 6144;

    bf16x8 qf[2];
    {
        const unsigned short* qrow = Qg + (wid * 16 + lrow) * DH + lgrp * 8;
        qf[0] = *(const bf16x8_ma*)(qrow);
        qf[1] = *(const bf16x8_ma*)(qrow + 32);
    }

    char* sPw = smem + wid * 2048;
    const int pswz = (lrow & 7) << 4;

    bf16x8 kf[8], vfA[16], vfB[16];
#define LOADK() do {                                                          \
        kf[0] = *(const bf16x8_ma*)(kp0);                                     \
        kf[1] = *(const bf16x8_ma*)(kp0 + 512);                               \
        kf[2] = *(const bf16x8_ma*)(kp0 + 1024);                              \
        kf[3] = *(const bf16x8_ma*)(kp0 + 1536);                              \
        kf[4] = *(const bf16x8_ma*)(kp1);                                     \
        kf[5] = *(const bf16x8_ma*)(kp1 + 512);                               \
        kf[6] = *(const bf16x8_ma*)(kp1 + 1024);                              \
        kf[7] = *(const bf16x8_ma*)(kp1 + 1536);                              \
        kp0 += 4096; kp1 += 4096;                                             \
    } while (0)
#define LOADVb(VF) do {                                                       \
        _Pragma("unroll")                                                     \
        for (int i_ = 0; i_ < 4; ++i_) {                                      \
            VF[i_]      = *(const bf16x8_ma*)(vp0 + i_ * 512);                \
            VF[4 + i_]  = *(const bf16x8_ma*)(vp1 + i_ * 512);                \
            VF[8 + i_]  = *(const bf16x8_ma*)(vp2 + i_ * 512);                \
            VF[12 + i_] = *(const bf16x8_ma*)(vp3 + i_ * 512);                \
        }                                                                     \
        vp0 += 8192; vp1 += 8192; vp2 += 8192; vp3 += 8192;                   \
    } while (0)
#define QKSM() do {                                                           \
        __builtin_amdgcn_s_setprio(1);                                        \
        _Pragma("unroll")                                                     \
        for (int nf = 0; nf < 4; ++nf) {                                      \
            st[nf] = (f32x4){0.f, 0.f, 0.f, 0.f};                             \
            st[nf] = __builtin_amdgcn_mfma_f32_16x16x32_bf16(kf[nf * 2],     qf[0], st[nf], 0, 0, 0); \
            st[nf] = __builtin_amdgcn_mfma_f32_16x16x32_bf16(kf[nf * 2 + 1], qf[1], st[nf], 0, 0, 0); \
        }                                                                     \
        __builtin_amdgcn_s_setprio(0);                                        \
        LOADK();                                                              \
        float rs = 0.f;                                                       \
        _Pragma("unroll")                                                     \
        for (int nf = 0; nf < 4; ++nf)                                        \
            _Pragma("unroll")                                                 \
            for (int r = 0; r < 4; ++r) {                                     \
                float p = exp2_raw(st[nf][r]);                                \
                st[nf][r] = p;                                                \
                rs += p;                                                      \
            }                                                                 \
        l_ += rs;                                                             \
        _Pragma("unroll")                                                     \
        for (int nf = 0; nf < 4; ++nf) {                                      \
            uint2 w;                                                          \
            w.x = cvt_pk_bf16(st[nf][0], st[nf][1]);                          \
            w.y = cvt_pk_bf16(st[nf][2], st[nf][3]);                          \
            *(uint2_ma*)(sPw + ((lrow * 128 + nf * 32 + lgrp * 8) ^ pswz)) = w; \
        }                                                                     \
    } while (0)
#define PVC(VF) do {                                                          \
        __builtin_amdgcn_s_setprio(1);                                        \
        _Pragma("unroll")                                                     \
        for (int kkv = 0; kkv < 2; ++kkv) {                                   \
            bf16x8 pf = *(bf16x8_ma*)(sPw + ((lrow * 128 + kkv * 64 + lgrp * 16) ^ pswz)); \
            _Pragma("unroll")                                                 \
            for (int df = 0; df < 8; ++df)                                    \
                oacc[df] = __builtin_amdgcn_mfma_f32_16x16x32_bf16(VF[df * 2 + kkv], pf, oacc[df], 0, 0, 0); \
        }                                                                     \
        __builtin_amdgcn_s_setprio(0);                                        \
    } while (0)

    f32x4 oacc[8];
#pragma unroll
    for (int df = 0; df < 8; ++df) oacc[df] = (f32x4){0.f, 0.f, 0.f, 0.f};
    float l_ = 0.f;
    f32x4 st[4];

    const int NT = NSEQ / 64;   // 32, even
    LOADK();                     // K tile 0
    LOADVb(vfA);                 // V tile 0

    for (int t = 0; t < NT; t += 2) {
        // even sub-iter: consume vfA (tile t), prefetch vfB (tile t+1)
        LOADVb(vfB);
        QKSM();                  // QK(t) + K-prefetch(t+1) + softmax + P
        PVC(vfA);
        // odd sub-iter: consume vfB (tile t+1), prefetch vfA (tile t+2)
        LOADVb(vfA);             // last pair over-reads past V region: valid ws, unused
        QKSM();
        PVC(vfB);
    }
#undef LOADK
#undef LOADVb
#undef QKSM
#undef PVC

    // ---- final l reduction (once, not per tile) ----
    l_ += __shfl_xor(l_, 16);
    l_ += __shfl_xor(l_, 32);

    // ---- retrieval epilogue (register-only; u = x@Wc already has 0.125*log2e;
    //      the 2^8 on oacc and l_ cancels in s*invl and in O*invl) ----
    {
        const int n = qt * 64 + wid * 16 + lrow;
        const float* ug = RU + ((((size_t)(b * NS + s)) * NSEQ) + n) * DH + lgrp * 4;
        float s0 = 0.f, s1 = 0.f;
#pragma unroll
        for (int df = 0; df < 4; ++df) {
            float4 u4 = *(const float4_ma*)(ug + df * 16);
            s0 += oacc[df][0] * u4.x + oacc[df][1] * u4.y + oacc[df][2] * u4.z + oacc[df][3] * u4.w;
            s1 += oacc[df + 4][0] * u4.x + oacc[df + 4][1] * u4.y + oacc[df + 4][2] * u4.z + oacc[df + 4][3] * u4.w;
        }
        s0 += __shfl_xor(s0, 16); s0 += __shfl_xor(s0, 32);
        s1 += __shfl_xor(s1, 16); s1 += __shfl_xor(s1, 32);
        float invl = 1.f / l_;
        float r0v = s0 * invl, r1v = s1 * invl;
        float mm = fmaxf(r0v, r1v);
        float e0 = exp2_raw(r0v - mm), e1 = exp2_raw(r1v - mm);
        float w = invl / (e0 + e1);
        float a0 = e0 * w, a1 = e1 * w;

        unsigned short* dst = O1b + ((size_t)(b * NSEQ + n)) * (NS * DH) + s * DH + lgrp * 4;
#pragma unroll
        for (int df = 0; df < 4; ++df) {
            float c0 = a0 * oacc[df][0] + a1 * oacc[df + 4][0];
            float c1 = a0 * oacc[df][1] + a1 * oacc[df + 4][1];
            float c2 = a0 * oacc[df][2] + a1 * oacc[df + 4][2];
            float c3 = a0 * oacc[df][3] + a1 * oacc[df + 4][3];
            uint2 o2;
            o2.x = cvt_pk_bf16(c0, c1);
            o2.y = cvt_pk_bf16(c2, c3);
            *(uint2_ma*)(dst + df * 16) = o2;
        }
    }
}

// ============ Kernel 3: output GEMM (bf16 MFMA, BN=128, global_load_lds) ============
__global__ __launch_bounds__(256) void out_mfma_k(
    const unsigned short* __restrict__ A, const unsigned short* __restrict__ Bw,
    float* __restrict__ C)
{
    __shared__ __align__(16) char smem[32768];
    const int tid = threadIdx.x;
    const int bn = blockIdx.x, bm = blockIdx.y;   // bn 0..7
    const int wid = tid >> 6, lane = tid & 63;
    const int wm = wid >> 1, wn = wid & 1;
    const int lrow = lane & 15, lgrp = lane >> 4;
    const int lr = lane >> 3, lc = lane & 7;
    const int KD = NS * DH;   // 512

    f32x4 acc[4][4];
#pragma unroll
    for (int i = 0; i < 4; ++i)
#pragma unroll
        for (int j = 0; j < 4; ++j) acc[i][j] = (f32x4){0.f, 0.f, 0.f, 0.f};

    for (int kt = 0; kt < KD / 64; ++kt) {
        __syncthreads();
#pragma unroll
        for (int i = 0; i < 4; ++i) {
            int seg = wid * 4 + i;
            int r = seg * 8 + lr;
            gld_lds16(smem + seg * 1024,
                      A + (size_t)(bm * 128 + r) * KD + kt * 64 + (lc ^ (r & 7)) * 8);
            gld_lds16(smem + 16384 + seg * 1024,
                      Bw + (size_t)(bn * 128 + r) * KD + kt * 64 + (lc ^ (r & 7)) * 8);
        }
        __syncthreads();
#pragma unroll
        for (int ks = 0; ks < 2; ++ks) {
            bf16x8 bfr[4];
#pragma unroll
            for (int nf = 0; nf < 4; ++nf) {
                int rb = wn * 64 + nf * 16 + lrow;
                bfr[nf] = *(bf16x8_ma*)(smem + 16384 + ((rb * 128 + ks * 64 + lgrp * 16) ^ ((rb & 7) << 4)));
            }
#pragma unroll
            for (int mf = 0; mf < 4; ++mf) {
                int ra = wm * 64 + mf * 16 + lrow;
                bf16x8 af = *(bf16x8_ma*)(smem + ((ra * 128 + ks * 64 + lgrp * 16) ^ ((ra & 7) << 4)));
#pragma unroll
                for (int nf = 0; nf < 4; ++nf)
                    acc[mf][nf] = __builtin_amdgcn_mfma_f32_16x16x32_bf16(af, bfr[nf], acc[mf][nf], 0, 0, 0);
            }
        }
    }

#pragma unroll
    for (int mf = 0; mf < 4; ++mf) {
#pragma unroll
        for (int nf = 0; nf < 4; ++nf) {
            int j0 = bn * 128 + wn * 64 + nf * 16 + lrow;
            int m0 = bm * 128 + wm * 64 + mf * 16 + lgrp * 4;
#pragma unroll
            for (int r = 0; r < 4; ++r)
                C[(size_t)(m0 + r) * KDIM + j0] = acc[mf][nf][r];
        }
    }
}

extern "C" void kernel_launch(void* const* d_in, const int* in_sizes, int n_in,
                              void* d_out, int out_size, void* d_ws, size_t ws_size,
                              hipStream_t stream)
{
    const float* x    = (const float*)d_in[0];
    const float* Wsq  = (const float*)d_in[1];
    const float* Wsk  = (const float*)d_in[2];
    const float* Wrv  = (const float*)d_in[3];
    const float* Wrq  = (const float*)d_in[4];
    const float* Wrk  = (const float*)d_in[5];
    const float* Wout = (const float*)d_in[6];
    float* out = (float*)d_out;

    // workspace layout (R15 layout)
    float* RU            = (float*)d_ws;                        // [2][8][2048][64] f32, 8 MB
    unsigned short* Wt   = (unsigned short*)(RU + (size_t)2 * NS * NSEQ * DH);  // [1664][1024], 3.25 MB
    unsigned short* Wot  = Wt + (size_t)1664 * KDIM;            // [1024][512], 1 MB
    unsigned short* Qb   = Wot + (size_t)KDIM * 512;            // [2][8][2048][64], 4 MB
    unsigned short* Kfr  = Qb + (size_t)2 * NS * NSEQ * DH;     // fragmented K, 4 MB
    unsigned short* Vfr  = Kfr + (size_t)2 * NS * NSEQ * DH;    // fragmented V, 1 MB
    unsigned short* xh   = Vfr + (size_t)2 * 128 * NSEQ;        // [4096][1024], 8 MB
    unsigned short* O1b  = xh;  // alias: xh dead after proj_mfma_k

    prep_all_k<<<2720, 256, 0, stream>>>(Wsq, Wsk, Wrq, Wrv, Wout, Wrk, x, Wt, Wot, xh);
    proj_mfma_k<<<dim3(13, 32), 256, 0, stream>>>(xh, Wt, Qb, Kfr, RU, Vfr);
    attn_mfma_k<<<512, 256, 0, stream>>>(Qb, Kfr, Vfr, RU, O1b);
    out_mfma_k<<<dim3(8, 32), 256, 0, stream>>>(O1b, Wot, out);
}

// Round 19
// 106.986 us; speedup vs baseline: 1.0382x; 1.0382x over previous
//
#include <hip/hip_runtime.h>

#define NSEQ 2048
#define KDIM 1024
#define DH   64
#define NS   8
#define NR   2

typedef short bf16x8 __attribute__((ext_vector_type(8)));
typedef float f32x4  __attribute__((ext_vector_type(4)));

typedef unsigned short ushort_ma __attribute__((may_alias));
typedef bf16x8         bf16x8_ma __attribute__((may_alias));
typedef uint4          uint4_ma  __attribute__((may_alias));
typedef uint2          uint2_ma  __attribute__((may_alias));
typedef float4         float4_ma __attribute__((may_alias));

__device__ __forceinline__ unsigned short f2bf(float f) {
    unsigned int u = __builtin_bit_cast(unsigned int, f);
    u = (u + 0x7FFFu + ((u >> 16) & 1u)) >> 16;   // RTN-even
    return (unsigned short)u;
}
__device__ __forceinline__ float bf2f(unsigned short h) {
    unsigned int u = ((unsigned int)h) << 16;
    return __builtin_bit_cast(float, u);
}
__device__ __forceinline__ unsigned int cvt_pk_bf16(float lo, float hi) {
    unsigned int r;
    asm("v_cvt_pk_bf16_f32 %0, %1, %2" : "=v"(r) : "v"(lo), "v"(hi));
    return r;
}
// raw v_exp_f32 (no denormal-guard sequence); inputs here are in [-30, +8]
__device__ __forceinline__ float exp2_raw(float x) {
    return __builtin_amdgcn_exp2f(x);
}
// async global->LDS, 16B/lane. LDS dest = wave-uniform base + lane*16 (m104).
__device__ __forceinline__ void gld_lds16(void* lptr, const void* gptr) {
    __builtin_amdgcn_global_load_lds(
        (const __attribute__((address_space(1))) unsigned int*)gptr,
        (__attribute__((address_space(3))) unsigned int*)lptr, 16, 0, 0);
}

// ============ prep (merged): weights transpose + Wc + x->bf16 ============
// blocks [0,544): Wt/Wot transpose; [544,672): Wc = Wrq_s @ Wrk^T; [672,2720): x->bf16.
__global__ __launch_bounds__(256) void prep_all_k(
    const float* __restrict__ Wsq, const float* __restrict__ Wsk,
    const float* __restrict__ Wrq, const float* __restrict__ Wrv,
    const float* __restrict__ Wout, const float* __restrict__ Wrk,
    const float* __restrict__ x,
    unsigned short* __restrict__ Wt, unsigned short* __restrict__ Wot,
    unsigned short* __restrict__ xh)
{
    __shared__ float sBuf[2][64][65];
    const int tid = threadIdx.x;
    const int bid = blockIdx.x;

    if (bid >= 672) {
        // ---- x -> bf16 (single plane; x-rounding ~0.1-0.2% rel, in budget) ----
        const int total = 4096 * KDIM / 4;
        int idx = (bid - 672) * 256 + tid;
        for (int i = idx; i < total; i += 2048 * 256) {
            float4 v = ((const float4_ma*)x)[i];
            ushort4 h;
            h.x = f2bf(v.x); h.y = f2bf(v.y); h.z = f2bf(v.z); h.w = f2bf(v.w);
            ((ushort4*)xh)[i] = h;
        }
        return;
    }

    if (bid >= 544) {
        // ---- Wc_s = Wrq[:, s*64:+64] @ Wrk^T -> Wt rows [1024+s*64, +64) ----
        const int r = bid - 544;
        const int s = r & 7;
        const int k0 = (r >> 3) * 64;
        float (*sQ)[65] = sBuf[0];
        float (*sK)[65] = sBuf[1];
#pragma unroll
        for (int p = 0; p < 4; ++p) {
            int row = (tid >> 4) + p * 16;
            int col = (tid & 15) * 4;
            float4 w = *(const float4*)&Wrk[(size_t)row * 64 + col];
            sK[row][col + 0] = w.x; sK[row][col + 1] = w.y;
            sK[row][col + 2] = w.z; sK[row][col + 3] = w.w;
            float4 q = *(const float4*)&Wrq[(size_t)(k0 + row) * 512 + s * 64 + col];
            sQ[row][col + 0] = q.x; sQ[row][col + 1] = q.y;
            sQ[row][col + 2] = q.z; sQ[row][col + 3] = q.w;
        }
        __syncthreads();

        const int dd = tid >> 2;
        const int kq = (tid & 3) * 16;
        float acc[16];
#pragma unroll
        for (int j = 0; j < 16; ++j) acc[j] = 0.f;
        for (int e = 0; e < 64; ++e) {
            float w = sK[dd][e];
#pragma unroll
            for (int j = 0; j < 16; ++j) acc[j] += w * sQ[kq + j][e];
        }
        const float SC = 0.125f * 1.44269504089f;
        unsigned int w8[8];
#pragma unroll
        for (int j = 0; j < 8; ++j)
            w8[j] = (unsigned)f2bf(acc[2 * j] * SC) | ((unsigned)f2bf(acc[2 * j + 1] * SC) << 16);
        unsigned short* o = Wt + (size_t)(1024 + s * 64 + dd) * KDIM + k0 + kq;
        *(uint4_ma*)o       = make_uint4(w8[0], w8[1], w8[2], w8[3]);
        *(uint4_ma*)(o + 8) = make_uint4(w8[4], w8[5], w8[6], w8[7]);
        return;
    }

    // ---- weight transpose + f32->bf16 ----
    {
        const float* src; int ldw, k0, n0, scol, ldo;
        unsigned short* dst;
        float sc = 1.0f;
        if (bid < 416) {
            int kt = bid / 26, nt = bid % 26;
            k0 = kt * 64; n0 = nt * 64;
            if (n0 >= 1024 && n0 < 1536) return;   // Wc section handled above
            if (n0 < 512)       { src = Wsq; ldw = 512; scol = n0;        sc = 0.125f * 1.44269504089f; }
            else if (n0 < 1024) { src = Wsk; ldw = 512; scol = n0 - 512;  }
            else                { src = Wrv; ldw = 128; scol = n0 - 1536; }
            dst = Wt; ldo = KDIM;
        } else {
            int r = bid - 416;
            int kt = r >> 4, nt = r & 15;
            k0 = kt * 64; n0 = nt * 64; scol = n0;
            src = Wout; ldw = KDIM;
            dst = Wot; ldo = 512;
        }
        float (*sT)[65] = sBuf[0];
#pragma unroll
        for (int p = 0; p < 4; ++p) {
            int row = (tid >> 4) + p * 16;
            int col = (tid & 15) * 4;
            float4 v = *(const float4*)&src[(size_t)(k0 + row) * ldw + scol + col];
            sT[row][col + 0] = v.x; sT[row][col + 1] = v.y;
            sT[row][col + 2] = v.z; sT[row][col + 3] = v.w;
        }
        __syncthreads();

        int n_l = tid >> 2, kg = (tid & 3) * 16;
        unsigned int w[8];
#pragma unroll
        for (int j = 0; j < 8; ++j) {
            unsigned short a = f2bf(sT[kg + 2 * j][n_l] * sc);
            unsigned short b = f2bf(sT[kg + 2 * j + 1][n_l] * sc);
            w[j] = (unsigned)a | ((unsigned)b << 16);
        }
        unsigned short* o = dst + (size_t)(n0 + n_l) * ldo + k0 + kg;
        *(uint4_ma*)o       = make_uint4(w[0], w[1], w[2], w[3]);
        *(uint4_ma*)(o + 8) = make_uint4(w[4], w[5], w[6], w[7]);
    }
}

// ============ Kernel 1: projection GEMM (bf16 MFMA, BN=128, single-x) ============
// RUb now bf16 (u is O(1); 0.4% rounding perturbs 2-way softmax weights <0.1%).
__global__ __launch_bounds__(256) void proj_mfma_k(
    const unsigned short* __restrict__ xh,
    const unsigned short* __restrict__ Wt,
    unsigned short* __restrict__ Qb, unsigned short* __restrict__ Kf,
    unsigned short* __restrict__ RUb, unsigned short* __restrict__ Vf)
{
    __shared__ __align__(16) char smem[32768];
    const int tid = threadIdx.x;
    const int bn = blockIdx.x, bm = blockIdx.y;   // bn 0..12
    const int wid = tid >> 6, lane = tid & 63;
    const int wm = wid >> 1, wn = wid & 1;
    const int lrow = lane & 15, lgrp = lane >> 4;
    const int lr = lane >> 3, lc = lane & 7;

    f32x4 acc[4][4];
#pragma unroll
    for (int i = 0; i < 4; ++i)
#pragma unroll
        for (int j = 0; j < 4; ++j) acc[i][j] = (f32x4){0.f, 0.f, 0.f, 0.f};

    for (int kt = 0; kt < KDIM / 64; ++kt) {
        __syncthreads();
#pragma unroll
        for (int i = 0; i < 4; ++i) {
            int seg = wid * 4 + i;
            int r = seg * 8 + lr;
            gld_lds16(smem + seg * 1024,
                      xh + (size_t)(bm * 128 + r) * KDIM + kt * 64 + (lc ^ (r & 7)) * 8);
            gld_lds16(smem + 16384 + seg * 1024,
                      Wt + (size_t)(bn * 128 + r) * KDIM + kt * 64 + (lc ^ (r & 7)) * 8);
        }
        __syncthreads();
#pragma unroll
        for (int ks = 0; ks < 2; ++ks) {
            bf16x8 bfr[4];
#pragma unroll
            for (int nf = 0; nf < 4; ++nf) {
                int rb = wn * 64 + nf * 16 + lrow;
                bfr[nf] = *(bf16x8_ma*)(smem + 16384 + ((rb * 128 + ks * 64 + lgrp * 16) ^ ((rb & 7) << 4)));
            }
#pragma unroll
            for (int mf = 0; mf < 4; ++mf) {
                int ra = wm * 64 + mf * 16 + lrow;
                bf16x8 ah = *(bf16x8_ma*)(smem + ((ra * 128 + ks * 64 + lgrp * 16) ^ ((ra & 7) << 4)));
#pragma unroll
                for (int nf = 0; nf < 4; ++nf)
                    acc[mf][nf] = __builtin_amdgcn_mfma_f32_16x16x32_bf16(ah, bfr[nf], acc[mf][nf], 0, 0, 0);
            }
        }
    }

    const int g = bn >> 2;   // bn 0-3:Q 4-7:K 8-11:U 12:V
#pragma unroll
    for (int mf = 0; mf < 4; ++mf) {
#pragma unroll
        for (int nf = 0; nf < 4; ++nf) {
            int j0 = bn * 128 + wn * 64 + nf * 16 + lrow;
            int m0 = bm * 128 + wm * 64 + mf * 16 + lgrp * 4;
            if (g == 3) {
                int dv = j0 - 1536;
                int bb = m0 >> 11, seq = m0 & (NSEQ - 1);
                size_t addr = (size_t)bb * 262144 + (size_t)(seq >> 6) * 8192
                    + (size_t)(((dv >> 4) * 2 + ((seq >> 5) & 1)) * 512)
                    + (((seq >> 3) & 3) * 16 + (dv & 15)) * 8 + (seq & 7);
                ushort4 h;
                h.x = f2bf(acc[mf][nf][0]); h.y = f2bf(acc[mf][nf][1]);
                h.z = f2bf(acc[mf][nf][2]); h.w = f2bf(acc[mf][nf][3]);
                *(ushort4*)&Vf[addr] = h;
            } else if (g == 1) {
                int s = (j0 >> 6) & 7, d = j0 & 63;
#pragma unroll
                for (int r = 0; r < 4; ++r) {
                    int m = m0 + r;
                    int bb = m >> 11, seq = m & (NSEQ - 1);
                    size_t base = ((size_t)(bb * NS + s)) * (NSEQ * DH)
                        + (size_t)(seq >> 6) * 4096
                        + ((((seq >> 4) & 3) * 2 + (d >> 5)) * 64
                           + ((d & 31) >> 3) * 16 + (seq & 15)) * 8 + (d & 7);
                    Kf[base] = f2bf(acc[mf][nf][r]);
                }
            } else {
                int s = (j0 >> 6) & 7, d = j0 & 63;
                unsigned short* basep = (g == 0) ? Qb : RUb;
#pragma unroll
                for (int r = 0; r < 4; ++r) {
                    int m = m0 + r;
                    int bb = m >> 11, seq = m & (NSEQ - 1);
                    basep[(((size_t)(bb * NS + s)) * NSEQ + seq) * DH + d] = f2bf(acc[mf][nf][r]);
                }
            }
        }
    }
}

// ============ Kernel 2: barrier-free fragment-direct attention (R17 verbatim) ============
// P' = exp2_raw(st) (no bias; 2^8 scale cancels in normalization and retrieval dot).
__global__ __launch_bounds__(256) void attn_mfma_k(
    const unsigned short* __restrict__ Qb, const unsigned short* __restrict__ Kfr,
    const unsigned short* __restrict__ Vfr, const unsigned short* __restrict__ RUb,
    unsigned short* __restrict__ O1b)
{
    __shared__ __align__(16) char smem[8192];
    const int tid = threadIdx.x;
    const int gblk = blockIdx.x;
    const int orig = ((gblk & 7) << 6) + (gblk >> 3);   // XCD-contiguous remap
    const int qt = orig & 31, s = (orig >> 5) & 7, b = orig >> 8;
    const int wid = tid >> 6, lane = tid & 63;
    const int lrow = lane & 15, lgrp = lane >> 4;

    const unsigned short* Qg = Qb + (((size_t)(b * NS + s)) * NSEQ + qt * 64) * DH;
    const unsigned short* kp0 = Kfr + ((size_t)(b * NS + s)) * (NSEQ * DH) + lane * 8;
    const unsigned short* kp1 = kp0 + 2048;
    const unsigned short* vp0 = Vfr + (size_t)b * 262144 + lane * 8;
    const unsigned short* vp1 = vp0 + 2048;
    const unsigned short* vp2 = vp0 + 4096;
    const unsigned short* vp3 = vp0 + 6144;

    bf16x8 qf[2];
    {
        const unsigned short* qrow = Qg + (wid * 16 + lrow) * DH + lgrp * 8;
        qf[0] = *(const bf16x8_ma*)(qrow);
        qf[1] = *(const bf16x8_ma*)(qrow + 32);
    }

    char* sPw = smem + wid * 2048;
    const int pswz = (lrow & 7) << 4;

    bf16x8 kf[8], vf[16];
#define LOADK() do {                                                          \
        kf[0] = *(const bf16x8_ma*)(kp0);                                     \
        kf[1] = *(const bf16x8_ma*)(kp0 + 512);                               \
        kf[2] = *(const bf16x8_ma*)(kp0 + 1024);                              \
        kf[3] = *(const bf16x8_ma*)(kp0 + 1536);                              \
        kf[4] = *(const bf16x8_ma*)(kp1);                                     \
        kf[5] = *(const bf16x8_ma*)(kp1 + 512);                               \
        kf[6] = *(const bf16x8_ma*)(kp1 + 1024);                              \
        kf[7] = *(const bf16x8_ma*)(kp1 + 1536);                              \
        kp0 += 4096; kp1 += 4096;                                             \
    } while (0)
#define LOADV() do {                                                          \
        _Pragma("unroll")                                                     \
        for (int i_ = 0; i_ < 4; ++i_) {                                      \
            vf[i_]      = *(const bf16x8_ma*)(vp0 + i_ * 512);                \
            vf[4 + i_]  = *(const bf16x8_ma*)(vp1 + i_ * 512);                \
            vf[8 + i_]  = *(const bf16x8_ma*)(vp2 + i_ * 512);                \
            vf[12 + i_] = *(const bf16x8_ma*)(vp3 + i_ * 512);                \
        }                                                                     \
        vp0 += 8192; vp1 += 8192; vp2 += 8192; vp3 += 8192;                   \
    } while (0)

    f32x4 oacc[8];
#pragma unroll
    for (int df = 0; df < 8; ++df) oacc[df] = (f32x4){0.f, 0.f, 0.f, 0.f};
    float l_ = 0.f;
    f32x4 st[4];

    const int NT = NSEQ / 64;
    LOADK();

    for (int t = 0; t < NT; ++t) {
        LOADV();   // tile t, in flight through QK + softmax

        __builtin_amdgcn_s_setprio(1);
#pragma unroll
        for (int nf = 0; nf < 4; ++nf) {
            st[nf] = (f32x4){0.f, 0.f, 0.f, 0.f};
            st[nf] = __builtin_amdgcn_mfma_f32_16x16x32_bf16(kf[nf * 2],     qf[0], st[nf], 0, 0, 0);
            st[nf] = __builtin_amdgcn_mfma_f32_16x16x32_bf16(kf[nf * 2 + 1], qf[1], st[nf], 0, 0, 0);
        }
        __builtin_amdgcn_s_setprio(0);

        LOADK();   // tile t+1 (last iter: harmless over-read, unused)

        // softmax: P' = exp2_raw(st) (scale 2^8 cancels in normalization)
        float rs = 0.f;
#pragma unroll
        for (int nf = 0; nf < 4; ++nf)
#pragma unroll
            for (int r = 0; r < 4; ++r) {
                float p = exp2_raw(st[nf][r]);
                st[nf][r] = p;
                rs += p;
            }
        l_ += rs;

#pragma unroll
        for (int nf = 0; nf < 4; ++nf) {
            uint2 w;
            w.x = cvt_pk_bf16(st[nf][0], st[nf][1]);
            w.y = cvt_pk_bf16(st[nf][2], st[nf][3]);
            *(uint2_ma*)(sPw + ((lrow * 128 + nf * 32 + lgrp * 8) ^ pswz)) = w;
        }

        __builtin_amdgcn_s_setprio(1);
#pragma unroll
        for (int kkv = 0; kkv < 2; ++kkv) {
            bf16x8 pf = *(bf16x8_ma*)(sPw + ((lrow * 128 + kkv * 64 + lgrp * 16) ^ pswz));
#pragma unroll
            for (int df = 0; df < 8; ++df)
                oacc[df] = __builtin_amdgcn_mfma_f32_16x16x32_bf16(vf[df * 2 + kkv], pf, oacc[df], 0, 0, 0);
        }
        __builtin_amdgcn_s_setprio(0);
    }
#undef LOADK
#undef LOADV

    // ---- final l reduction (once, not per tile) ----
    l_ += __shfl_xor(l_, 16);
    l_ += __shfl_xor(l_, 32);

    // ---- retrieval epilogue (register-only; u = x@Wc already has 0.125*log2e;
    //      the 2^8 on oacc and l_ cancels in s*invl and in O*invl) ----
    {
        const int n = qt * 64 + wid * 16 + lrow;
        const unsigned short* ug = RUb + ((((size_t)(b * NS + s)) * NSEQ) + n) * DH + lgrp * 4;
        float s0 = 0.f, s1 = 0.f;
#pragma unroll
        for (int df = 0; df < 4; ++df) {
            ushort4 u4 = *(const ushort4*)(ug + df * 16);
            float ux = bf2f(u4.x), uy = bf2f(u4.y), uz = bf2f(u4.z), uw = bf2f(u4.w);
            s0 += oacc[df][0] * ux + oacc[df][1] * uy + oacc[df][2] * uz + oacc[df][3] * uw;
            s1 += oacc[df + 4][0] * ux + oacc[df + 4][1] * uy + oacc[df + 4][2] * uz + oacc[df + 4][3] * uw;
        }
        s0 += __shfl_xor(s0, 16); s0 += __shfl_xor(s0, 32);
        s1 += __shfl_xor(s1, 16); s1 += __shfl_xor(s1, 32);
        float invl = 1.f / l_;
        float r0v = s0 * invl, r1v = s1 * invl;
        float mm = fmaxf(r0v, r1v);
        float e0 = exp2_raw(r0v - mm), e1 = exp2_raw(r1v - mm);
        float w = invl / (e0 + e1);
        float a0 = e0 * w, a1 = e1 * w;

        unsigned short* dst = O1b + ((size_t)(b * NSEQ + n)) * (NS * DH) + s * DH + lgrp * 4;
#pragma unroll
        for (int df = 0; df < 4; ++df) {
            float c0 = a0 * oacc[df][0] + a1 * oacc[df + 4][0];
            float c1 = a0 * oacc[df][1] + a1 * oacc[df + 4][1];
            float c2 = a0 * oacc[df][2] + a1 * oacc[df + 4][2];
            float c3 = a0 * oacc[df][3] + a1 * oacc[df + 4][3];
            uint2 o2;
            o2.x = cvt_pk_bf16(c0, c1);
            o2.y = cvt_pk_bf16(c2, c3);
            *(uint2_ma*)(dst + df * 16) = o2;
        }
    }
}

// ============ Kernel 3: output GEMM (bf16 MFMA, BN=128, global_load_lds) ============
__global__ __launch_bounds__(256) void out_mfma_k(
    const unsigned short* __restrict__ A, const unsigned short* __restrict__ Bw,
    float* __restrict__ C)
{
    __shared__ __align__(16) char smem[32768];
    const int tid = threadIdx.x;
    const int bn = blockIdx.x, bm = blockIdx.y;   // bn 0..7
    const int wid = tid >> 6, lane = tid & 63;
    const int wm = wid >> 1, wn = wid & 1;
    const int lrow = lane & 15, lgrp = lane >> 4;
    const int lr = lane >> 3, lc = lane & 7;
    const int KD = NS * DH;   // 512

    f32x4 acc[4][4];
#pragma unroll
    for (int i = 0; i < 4; ++i)
#pragma unroll
        for (int j = 0; j < 4; ++j) acc[i][j] = (f32x4){0.f, 0.f, 0.f, 0.f};

    for (int kt = 0; kt < KD / 64; ++kt) {
        __syncthreads();
#pragma unroll
        for (int i = 0; i < 4; ++i) {
            int seg = wid * 4 + i;
            int r = seg * 8 + lr;
            gld_lds16(smem + seg * 1024,
                      A + (size_t)(bm * 128 + r) * KD + kt * 64 + (lc ^ (r & 7)) * 8);
            gld_lds16(smem + 16384 + seg * 1024,
                      Bw + (size_t)(bn * 128 + r) * KD + kt * 64 + (lc ^ (r & 7)) * 8);
        }
        __syncthreads();
#pragma unroll
        for (int ks = 0; ks < 2; ++ks) {
            bf16x8 bfr[4];
#pragma unroll
            for (int nf = 0; nf < 4; ++nf) {
                int rb = wn * 64 + nf * 16 + lrow;
                bfr[nf] = *(bf16x8_ma*)(smem + 16384 + ((rb * 128 + ks * 64 + lgrp * 16) ^ ((rb & 7) << 4)));
            }
#pragma unroll
            for (int mf = 0; mf < 4; ++mf) {
                int ra = wm * 64 + mf * 16 + lrow;
                bf16x8 af = *(bf16x8_ma*)(smem + ((ra * 128 + ks * 64 + lgrp * 16) ^ ((ra & 7) << 4)));
#pragma unroll
                for (int nf = 0; nf < 4; ++nf)
                    acc[mf][nf] = __builtin_amdgcn_mfma_f32_16x16x32_bf16(af, bfr[nf], acc[mf][nf], 0, 0, 0);
            }
        }
    }

#pragma unroll
    for (int mf = 0; mf < 4; ++mf) {
#pragma unroll
        for (int nf = 0; nf < 4; ++nf) {
            int j0 = bn * 128 + wn * 64 + nf * 16 + lrow;
            int m0 = bm * 128 + wm * 64 + mf * 16 + lgrp * 4;
#pragma unroll
            for (int r = 0; r < 4; ++r)
                C[(size_t)(m0 + r) * KDIM + j0] = acc[mf][nf][r];
        }
    }
}

extern "C" void kernel_launch(void* const* d_in, const int* in_sizes, int n_in,
                              void* d_out, int out_size, void* d_ws, size_t ws_size,
                              hipStream_t stream)
{
    const float* x    = (const float*)d_in[0];
    const float* Wsq  = (const float*)d_in[1];
    const float* Wsk  = (const float*)d_in[2];
    const float* Wrv  = (const float*)d_in[3];
    const float* Wrq  = (const float*)d_in[4];
    const float* Wrk  = (const float*)d_in[5];
    const float* Wout = (const float*)d_in[6];
    float* out = (float*)d_out;

    // workspace layout (RUb now bf16, 4 MB; layout otherwise R15-compatible)
    unsigned short* RUb  = (unsigned short*)d_ws;               // [16][2048][64] bf16, 4 MB
    unsigned short* Wt   = RUb + (size_t)2 * NS * NSEQ * DH;    // [1664][1024], 3.25 MB
    unsigned short* Wot  = Wt + (size_t)1664 * KDIM;            // [1024][512], 1 MB
    unsigned short* Qb   = Wot + (size_t)KDIM * 512;            // [16][2048][64], 4 MB
    unsigned short* Kfr  = Qb + (size_t)2 * NS * NSEQ * DH;     // fragmented K, 4 MB
    unsigned short* Vfr  = Kfr + (size_t)2 * NS * NSEQ * DH;    // fragmented V, 1 MB
    unsigned short* xh   = Vfr + (size_t)2 * 128 * NSEQ;        // [4096][1024], 8 MB
    unsigned short* O1b  = xh;  // alias: xh dead after proj_mfma_k

    prep_all_k<<<2720, 256, 0, stream>>>(Wsq, Wsk, Wrq, Wrv, Wout, Wrk, x, Wt, Wot, xh);
    proj_mfma_k<<<dim3(13, 32), 256, 0, stream>>>(xh, Wt, Qb, Kfr, RUb, Vfr);
    attn_mfma_k<<<512, 256, 0, stream>>>(Qb, Kfr, Vfr, RUb, O1b);
    out_mfma_k<<<dim3(8, 32), 256, 0, stream>>>(O1b, Wot, out);
}

// Round 20
// 106.256 us; speedup vs baseline: 1.0453x; 1.0069x over previous
//
#include <hip/hip_runtime.h>

#define NSEQ 2048
#define KDIM 1024
#define DH   64
#define NS   8
#define NR   2

typedef short bf16x8 __attribute__((ext_vector_type(8)));
typedef float f32x4  __attribute__((ext_vector_type(4)));

typedef unsigned short ushort_ma __attribute__((may_alias));
typedef bf16x8         bf16x8_ma __attribute__((may_alias));
typedef uint4          uint4_ma  __attribute__((may_alias));
typedef uint2          uint2_ma  __attribute__((may_alias));
typedef float4         float4_ma __attribute__((may_alias));

__device__ __forceinline__ unsigned short f2bf(float f) {
    unsigned int u = __builtin_bit_cast(unsigned int, f);
    u = (u + 0x7FFFu + ((u >> 16) & 1u)) >> 16;   // RTN-even
    return (unsigned short)u;
}
__device__ __forceinline__ float bf2f(unsigned short h) {
    unsigned int u = ((unsigned int)h) << 16;
    return __builtin_bit_cast(float, u);
}
__device__ __forceinline__ unsigned int cvt_pk_bf16(float lo, float hi) {
    unsigned int r;
    asm("v_cvt_pk_bf16_f32 %0, %1, %2" : "=v"(r) : "v"(lo), "v"(hi));
    return r;
}
// raw v_exp_f32 (no denormal-guard sequence); inputs here are in [-30, +8]
__device__ __forceinline__ float exp2_raw(float x) {
    return __builtin_amdgcn_exp2f(x);
}
// async global->LDS, 16B/lane. LDS dest = wave-uniform base + lane*16 (m104).
__device__ __forceinline__ void gld_lds16(void* lptr, const void* gptr) {
    __builtin_amdgcn_global_load_lds(
        (const __attribute__((address_space(1))) unsigned int*)gptr,
        (__attribute__((address_space(3))) unsigned int*)lptr, 16, 0, 0);
}

// ============ prep (merged): weights transpose + Wc + x->bf16 ============
// blocks [0,544): Wt/Wot transpose; [544,672): Wc = Wrq_s @ Wrk^T; [672,2720): x->bf16.
__global__ __launch_bounds__(256) void prep_all_k(
    const float* __restrict__ Wsq, const float* __restrict__ Wsk,
    const float* __restrict__ Wrq, const float* __restrict__ Wrv,
    const float* __restrict__ Wout, const float* __restrict__ Wrk,
    const float* __restrict__ x,
    unsigned short* __restrict__ Wt, unsigned short* __restrict__ Wot,
    unsigned short* __restrict__ xh)
{
    __shared__ float sBuf[2][64][65];
    const int tid = threadIdx.x;
    const int bid = blockIdx.x;

    if (bid >= 672) {
        const int total = 4096 * KDIM / 4;
        int idx = (bid - 672) * 256 + tid;
        for (int i = idx; i < total; i += 2048 * 256) {
            float4 v = ((const float4_ma*)x)[i];
            ushort4 h;
            h.x = f2bf(v.x); h.y = f2bf(v.y); h.z = f2bf(v.z); h.w = f2bf(v.w);
            ((ushort4*)xh)[i] = h;
        }
        return;
    }

    if (bid >= 544) {
        const int r = bid - 544;
        const int s = r & 7;
        const int k0 = (r >> 3) * 64;
        float (*sQ)[65] = sBuf[0];
        float (*sK)[65] = sBuf[1];
#pragma unroll
        for (int p = 0; p < 4; ++p) {
            int row = (tid >> 4) + p * 16;
            int col = (tid & 15) * 4;
            float4 w = *(const float4*)&Wrk[(size_t)row * 64 + col];
            sK[row][col + 0] = w.x; sK[row][col + 1] = w.y;
            sK[row][col + 2] = w.z; sK[row][col + 3] = w.w;
            float4 q = *(const float4*)&Wrq[(size_t)(k0 + row) * 512 + s * 64 + col];
            sQ[row][col + 0] = q.x; sQ[row][col + 1] = q.y;
            sQ[row][col + 2] = q.z; sQ[row][col + 3] = q.w;
        }
        __syncthreads();

        const int dd = tid >> 2;
        const int kq = (tid & 3) * 16;
        float acc[16];
#pragma unroll
        for (int j = 0; j < 16; ++j) acc[j] = 0.f;
        for (int e = 0; e < 64; ++e) {
            float w = sK[dd][e];
#pragma unroll
            for (int j = 0; j < 16; ++j) acc[j] += w * sQ[kq + j][e];
        }
        const float SC = 0.125f * 1.44269504089f;
        unsigned int w8[8];
#pragma unroll
        for (int j = 0; j < 8; ++j)
            w8[j] = (unsigned)f2bf(acc[2 * j] * SC) | ((unsigned)f2bf(acc[2 * j + 1] * SC) << 16);
        unsigned short* o = Wt + (size_t)(1024 + s * 64 + dd) * KDIM + k0 + kq;
        *(uint4_ma*)o       = make_uint4(w8[0], w8[1], w8[2], w8[3]);
        *(uint4_ma*)(o + 8) = make_uint4(w8[4], w8[5], w8[6], w8[7]);
        return;
    }

    {
        const float* src; int ldw, k0, n0, scol, ldo;
        unsigned short* dst;
        float sc = 1.0f;
        if (bid < 416) {
            int kt = bid / 26, nt = bid % 26;
            k0 = kt * 64; n0 = nt * 64;
            if (n0 >= 1024 && n0 < 1536) return;
            if (n0 < 512)       { src = Wsq; ldw = 512; scol = n0;        sc = 0.125f * 1.44269504089f; }
            else if (n0 < 1024) { src = Wsk; ldw = 512; scol = n0 - 512;  }
            else                { src = Wrv; ldw = 128; scol = n0 - 1536; }
            dst = Wt; ldo = KDIM;
        } else {
            int r = bid - 416;
            int kt = r >> 4, nt = r & 15;
            k0 = kt * 64; n0 = nt * 64; scol = n0;
            src = Wout; ldw = KDIM;
            dst = Wot; ldo = 512;
        }
        float (*sT)[65] = sBuf[0];
#pragma unroll
        for (int p = 0; p < 4; ++p) {
            int row = (tid >> 4) + p * 16;
            int col = (tid & 15) * 4;
            float4 v = *(const float4*)&src[(size_t)(k0 + row) * ldw + scol + col];
            sT[row][col + 0] = v.x; sT[row][col + 1] = v.y;
            sT[row][col + 2] = v.z; sT[row][col + 3] = v.w;
        }
        __syncthreads();

        int n_l = tid >> 2, kg = (tid & 3) * 16;
        unsigned int w[8];
#pragma unroll
        for (int j = 0; j < 8; ++j) {
            unsigned short a = f2bf(sT[kg + 2 * j][n_l] * sc);
            unsigned short b = f2bf(sT[kg + 2 * j + 1][n_l] * sc);
            w[j] = (unsigned)a | ((unsigned)b << 16);
        }
        unsigned short* o = dst + (size_t)(n0 + n_l) * ldo + k0 + kg;
        *(uint4_ma*)o       = make_uint4(w[0], w[1], w[2], w[3]);
        *(uint4_ma*)(o + 8) = make_uint4(w[4], w[5], w[6], w[7]);
    }
}

// ============ Kernel 1: projection GEMM (bf16 MFMA, BN=128, single-x) ============
__global__ __launch_bounds__(256) void proj_mfma_k(
    const unsigned short* __restrict__ xh,
    const unsigned short* __restrict__ Wt,
    unsigned short* __restrict__ Qb, unsigned short* __restrict__ Kf,
    unsigned short* __restrict__ RUb, unsigned short* __restrict__ Vf)
{
    __shared__ __align__(16) char smem[32768];
    const int tid = threadIdx.x;
    const int bn = blockIdx.x, bm = blockIdx.y;   // bn 0..12
    const int wid = tid >> 6, lane = tid & 63;
    const int wm = wid >> 1, wn = wid & 1;
    const int lrow = lane & 15, lgrp = lane >> 4;
    const int lr = lane >> 3, lc = lane & 7;

    f32x4 acc[4][4];
#pragma unroll
    for (int i = 0; i < 4; ++i)
#pragma unroll
        for (int j = 0; j < 4; ++j) acc[i][j] = (f32x4){0.f, 0.f, 0.f, 0.f};

    for (int kt = 0; kt < KDIM / 64; ++kt) {
        __syncthreads();
#pragma unroll
        for (int i = 0; i < 4; ++i) {
            int seg = wid * 4 + i;
            int r = seg * 8 + lr;
            gld_lds16(smem + seg * 1024,
                      xh + (size_t)(bm * 128 + r) * KDIM + kt * 64 + (lc ^ (r & 7)) * 8);
            gld_lds16(smem + 16384 + seg * 1024,
                      Wt + (size_t)(bn * 128 + r) * KDIM + kt * 64 + (lc ^ (r & 7)) * 8);
        }
        __syncthreads();
#pragma unroll
        for (int ks = 0; ks < 2; ++ks) {
            bf16x8 bfr[4];
#pragma unroll
            for (int nf = 0; nf < 4; ++nf) {
                int rb = wn * 64 + nf * 16 + lrow;
                bfr[nf] = *(bf16x8_ma*)(smem + 16384 + ((rb * 128 + ks * 64 + lgrp * 16) ^ ((rb & 7) << 4)));
            }
#pragma unroll
            for (int mf = 0; mf < 4; ++mf) {
                int ra = wm * 64 + mf * 16 + lrow;
                bf16x8 ah = *(bf16x8_ma*)(smem + ((ra * 128 + ks * 64 + lgrp * 16) ^ ((ra & 7) << 4)));
#pragma unroll
                for (int nf = 0; nf < 4; ++nf)
                    acc[mf][nf] = __builtin_amdgcn_mfma_f32_16x16x32_bf16(ah, bfr[nf], acc[mf][nf], 0, 0, 0);
            }
        }
    }

    const int g = bn >> 2;   // bn 0-3:Q 4-7:K 8-11:U 12:V
#pragma unroll
    for (int mf = 0; mf < 4; ++mf) {
#pragma unroll
        for (int nf = 0; nf < 4; ++nf) {
            int j0 = bn * 128 + wn * 64 + nf * 16 + lrow;
            int m0 = bm * 128 + wm * 64 + mf * 16 + lgrp * 4;
            if (g == 3) {
                int dv = j0 - 1536;
                int bb = m0 >> 11, seq = m0 & (NSEQ - 1);
                size_t addr = (size_t)bb * 262144 + (size_t)(seq >> 6) * 8192
                    + (size_t)(((dv >> 4) * 2 + ((seq >> 5) & 1)) * 512)
                    + (((seq >> 3) & 3) * 16 + (dv & 15)) * 8 + (seq & 7);
                ushort4 h;
                h.x = f2bf(acc[mf][nf][0]); h.y = f2bf(acc[mf][nf][1]);
                h.z = f2bf(acc[mf][nf][2]); h.w = f2bf(acc[mf][nf][3]);
                *(ushort4*)&Vf[addr] = h;
            } else if (g == 1) {
                int s = (j0 >> 6) & 7, d = j0 & 63;
#pragma unroll
                for (int r = 0; r < 4; ++r) {
                    int m = m0 + r;
                    int bb = m >> 11, seq = m & (NSEQ - 1);
                    size_t base = ((size_t)(bb * NS + s)) * (NSEQ * DH)
                        + (size_t)(seq >> 6) * 4096
                        + ((((seq >> 4) & 3) * 2 + (d >> 5)) * 64
                           + ((d & 31) >> 3) * 16 + (seq & 15)) * 8 + (d & 7);
                    Kf[base] = f2bf(acc[mf][nf][r]);
                }
            } else {
                int s = (j0 >> 6) & 7, d = j0 & 63;
                unsigned short* basep = (g == 0) ? Qb : RUb;
#pragma unroll
                for (int r = 0; r < 4; ++r) {
                    int m = m0 + r;
                    int bb = m >> 11, seq = m & (NSEQ - 1);
                    basep[(((size_t)(bb * NS + s)) * NSEQ + seq) * DH + d] = f2bf(acc[mf][nf][r]);
                }
            }
        }
    }
}

// ============ Kernel 2: hand-pipelined fragment-direct attention ============
// ALL K/V loads are asm-volatile global_load_dwordx4 with hand-counted
// s_waitcnt vmcnt(N) + sched_barrier(0) (rule #18). Steady state: 24 loads
// outstanding (16 V + 8 K); vmcnt(16) at QK waits K(t) only; vmcnt(8) at PV
// waits V(t) only, K(t+1) stays in flight. No compiler vmem ops in the loop
// (LDS is lgkm-counted); explicit vmcnt(0) drain before epilogue keeps the
// compiler's own waitcnt accounting consistent. Tail over-issues read valid
// adjacent workspace (values unused).
__global__ __launch_bounds__(256) void attn_mfma_k(
    const unsigned short* __restrict__ Qb, const unsigned short* __restrict__ Kfr,
    const unsigned short* __restrict__ Vfr, const unsigned short* __restrict__ RUb,
    unsigned short* __restrict__ O1b)
{
    __shared__ __align__(16) char smem[8192];
    const int tid = threadIdx.x;
    const int gblk = blockIdx.x;
    const int orig = ((gblk & 7) << 6) + (gblk >> 3);   // XCD-contiguous remap
    const int qt = orig & 31, s = (orig >> 5) & 7, b = orig >> 8;
    const int wid = tid >> 6, lane = tid & 63;
    const int lrow = lane & 15, lgrp = lane >> 4;

    const unsigned short* Qg = Qb + (((size_t)(b * NS + s)) * NSEQ + qt * 64) * DH;
    const unsigned short* kp0 = Kfr + ((size_t)(b * NS + s)) * (NSEQ * DH) + lane * 8;
    const unsigned short* kp1 = kp0 + 2048;
    const unsigned short* vp0 = Vfr + (size_t)b * 262144 + lane * 8;
    const unsigned short* vp1 = vp0 + 2048;
    const unsigned short* vp2 = vp0 + 4096;
    const unsigned short* vp3 = vp0 + 6144;

    bf16x8 qf[2];
    {
        const unsigned short* qrow = Qg + (wid * 16 + lrow) * DH + lgrp * 8;
        qf[0] = *(const bf16x8_ma*)(qrow);
        qf[1] = *(const bf16x8_ma*)(qrow + 32);
    }

    char* sPw = smem + wid * 2048;
    const int pswz = (lrow & 7) << 4;

    bf16x8 kf[8], vf[16];
// 8 K-fragment loads (1KB/wave each, coalesced); advances pointers.
#define LOADK_ASM() do {                                                              \
    asm volatile("global_load_dwordx4 %0, %1, off"             : "=&v"(kf[0]) : "v"(kp0)); \
    asm volatile("global_load_dwordx4 %0, %1, off offset:1024" : "=&v"(kf[1]) : "v"(kp0)); \
    asm volatile("global_load_dwordx4 %0, %1, off offset:2048" : "=&v"(kf[2]) : "v"(kp0)); \
    asm volatile("global_load_dwordx4 %0, %1, off offset:3072" : "=&v"(kf[3]) : "v"(kp0)); \
    asm volatile("global_load_dwordx4 %0, %1, off"             : "=&v"(kf[4]) : "v"(kp1)); \
    asm volatile("global_load_dwordx4 %0, %1, off offset:1024" : "=&v"(kf[5]) : "v"(kp1)); \
    asm volatile("global_load_dwordx4 %0, %1, off offset:2048" : "=&v"(kf[6]) : "v"(kp1)); \
    asm volatile("global_load_dwordx4 %0, %1, off offset:3072" : "=&v"(kf[7]) : "v"(kp1)); \
    kp0 += 4096; kp1 += 4096;                                                         \
} while (0)
// 16 V-fragment loads; advances pointers.
#define LOADV_ASM() do {                                                              \
    asm volatile("global_load_dwordx4 %0, %1, off"             : "=&v"(vf[0])  : "v"(vp0)); \
    asm volatile("global_load_dwordx4 %0, %1, off offset:1024" : "=&v"(vf[1])  : "v"(vp0)); \
    asm volatile("global_load_dwordx4 %0, %1, off offset:2048" : "=&v"(vf[2])  : "v"(vp0)); \
    asm volatile("global_load_dwordx4 %0, %1, off offset:3072" : "=&v"(vf[3])  : "v"(vp0)); \
    asm volatile("global_load_dwordx4 %0, %1, off"             : "=&v"(vf[4])  : "v"(vp1)); \
    asm volatile("global_load_dwordx4 %0, %1, off offset:1024" : "=&v"(vf[5])  : "v"(vp1)); \
    asm volatile("global_load_dwordx4 %0, %1, off offset:2048" : "=&v"(vf[6])  : "v"(vp1)); \
    asm volatile("global_load_dwordx4 %0, %1, off offset:3072" : "=&v"(vf[7])  : "v"(vp1)); \
    asm volatile("global_load_dwordx4 %0, %1, off"             : "=&v"(vf[8])  : "v"(vp2)); \
    asm volatile("global_load_dwordx4 %0, %1, off offset:1024" : "=&v"(vf[9])  : "v"(vp2)); \
    asm volatile("global_load_dwordx4 %0, %1, off offset:2048" : "=&v"(vf[10]) : "v"(vp2)); \
    asm volatile("global_load_dwordx4 %0, %1, off offset:3072" : "=&v"(vf[11]) : "v"(vp2)); \
    asm volatile("global_load_dwordx4 %0, %1, off"             : "=&v"(vf[12]) : "v"(vp3)); \
    asm volatile("global_load_dwordx4 %0, %1, off offset:1024" : "=&v"(vf[13]) : "v"(vp3)); \
    asm volatile("global_load_dwordx4 %0, %1, off offset:2048" : "=&v"(vf[14]) : "v"(vp3)); \
    asm volatile("global_load_dwordx4 %0, %1, off offset:3072" : "=&v"(vf[15]) : "v"(vp3)); \
    vp0 += 8192; vp1 += 8192; vp2 += 8192; vp3 += 8192;                               \
} while (0)
#define WAITCNT(N) do {                                                       \
    asm volatile("s_waitcnt vmcnt(" #N ")" ::: "memory");                     \
    __builtin_amdgcn_sched_barrier(0);                                        \
} while (0)

    f32x4 oacc[8];
#pragma unroll
    for (int df = 0; df < 8; ++df) oacc[df] = (f32x4){0.f, 0.f, 0.f, 0.f};
    float l_ = 0.f;
    f32x4 st[4];

    const int NT = NSEQ / 64;
    LOADK_ASM();    // K(0)
    LOADV_ASM();    // V(0)   -> 24 outstanding

    for (int t = 0; t < NT; ++t) {
        WAITCNT(16);   // K(t) ready; 16 V(t) loads still in flight

        __builtin_amdgcn_s_setprio(1);
#pragma unroll
        for (int nf = 0; nf < 4; ++nf) {
            st[nf] = (f32x4){0.f, 0.f, 0.f, 0.f};
            st[nf] = __builtin_amdgcn_mfma_f32_16x16x32_bf16(kf[nf * 2],     qf[0], st[nf], 0, 0, 0);
            st[nf] = __builtin_amdgcn_mfma_f32_16x16x32_bf16(kf[nf * 2 + 1], qf[1], st[nf], 0, 0, 0);
        }
        __builtin_amdgcn_s_setprio(0);

        LOADK_ASM();   // K(t+1); last iter over-reads valid adjacent ws (unused)

        // softmax: P' = exp2_raw(st) (2^8 scale cancels in normalization)
        float rs = 0.f;
#pragma unroll
        for (int nf = 0; nf < 4; ++nf)
#pragma unroll
            for (int r = 0; r < 4; ++r) {
                float p = exp2_raw(st[nf][r]);
                st[nf][r] = p;
                rs += p;
            }
        l_ += rs;

#pragma unroll
        for (int nf = 0; nf < 4; ++nf) {
            uint2 w;
            w.x = cvt_pk_bf16(st[nf][0], st[nf][1]);
            w.y = cvt_pk_bf16(st[nf][2], st[nf][3]);
            *(uint2_ma*)(sPw + ((lrow * 128 + nf * 32 + lgrp * 8) ^ pswz)) = w;
        }

        WAITCNT(8);    // V(t) ready; 8 K(t+1) loads still in flight

        __builtin_amdgcn_s_setprio(1);
#pragma unroll
        for (int kkv = 0; kkv < 2; ++kkv) {
            bf16x8 pf = *(bf16x8_ma*)(sPw + ((lrow * 128 + kkv * 64 + lgrp * 16) ^ pswz));
#pragma unroll
            for (int df = 0; df < 8; ++df)
                oacc[df] = __builtin_amdgcn_mfma_f32_16x16x32_bf16(vf[df * 2 + kkv], pf, oacc[df], 0, 0, 0);
        }
        __builtin_amdgcn_s_setprio(0);

        LOADV_ASM();   // V(t+1); last iter over-reads valid adjacent ws (unused)
    }
    // drain everything before compiler-generated epilogue loads
    asm volatile("s_waitcnt vmcnt(0)" ::: "memory");
    __builtin_amdgcn_sched_barrier(0);
#undef LOADK_ASM
#undef LOADV_ASM
#undef WAITCNT

    // ---- final l reduction (once, not per tile) ----
    l_ += __shfl_xor(l_, 16);
    l_ += __shfl_xor(l_, 32);

    // ---- retrieval epilogue (register-only; u = x@Wc already has 0.125*log2e) ----
    {
        const int n = qt * 64 + wid * 16 + lrow;
        const unsigned short* ug = RUb + ((((size_t)(b * NS + s)) * NSEQ) + n) * DH + lgrp * 4;
        float s0 = 0.f, s1 = 0.f;
#pragma unroll
        for (int df = 0; df < 4; ++df) {
            ushort4 u4 = *(const ushort4*)(ug + df * 16);
            float ux = bf2f(u4.x), uy = bf2f(u4.y), uz = bf2f(u4.z), uw = bf2f(u4.w);
            s0 += oacc[df][0] * ux + oacc[df][1] * uy + oacc[df][2] * uz + oacc[df][3] * uw;
            s1 += oacc[df + 4][0] * ux + oacc[df + 4][1] * uy + oacc[df + 4][2] * uz + oacc[df + 4][3] * uw;
        }
        s0 += __shfl_xor(s0, 16); s0 += __shfl_xor(s0, 32);
        s1 += __shfl_xor(s1, 16); s1 += __shfl_xor(s1, 32);
        float invl = 1.f / l_;
        float r0v = s0 * invl, r1v = s1 * invl;
        float mm = fmaxf(r0v, r1v);
        float e0 = exp2_raw(r0v - mm), e1 = exp2_raw(r1v - mm);
        float w = invl / (e0 + e1);
        float a0 = e0 * w, a1 = e1 * w;

        unsigned short* dst = O1b + ((size_t)(b * NSEQ + n)) * (NS * DH) + s * DH + lgrp * 4;
#pragma unroll
        for (int df = 0; df < 4; ++df) {
            float c0 = a0 * oacc[df][0] + a1 * oacc[df + 4][0];
            float c1 = a0 * oacc[df][1] + a1 * oacc[df + 4][1];
            float c2 = a0 * oacc[df][2] + a1 * oacc[df + 4][2];
            float c3 = a0 * oacc[df][3] + a1 * oacc[df + 4][3];
            uint2 o2;
            o2.x = cvt_pk_bf16(c0, c1);
            o2.y = cvt_pk_bf16(c2, c3);
            *(uint2_ma*)(dst + df * 16) = o2;
        }
    }
}

// ============ Kernel 3: output GEMM (bf16 MFMA, BN=128, global_load_lds) ============
__global__ __launch_bounds__(256) void out_mfma_k(
    const unsigned short* __restrict__ A, const unsigned short* __restrict__ Bw,
    float* __restrict__ C)
{
    __shared__ __align__(16) char smem[32768];
    const int tid = threadIdx.x;
    const int bn = blockIdx.x, bm = blockIdx.y;   // bn 0..7
    const int wid = tid >> 6, lane = tid & 63;
    const int wm = wid >> 1, wn = wid & 1;
    const int lrow = lane & 15, lgrp = lane >> 4;
    const int lr = lane >> 3, lc = lane & 7;
    const int KD = NS * DH;   // 512

    f32x4 acc[4][4];
#pragma unroll
    for (int i = 0; i < 4; ++i)
#pragma unroll
        for (int j = 0; j < 4; ++j) acc[i][j] = (f32x4){0.f, 0.f, 0.f, 0.f};

    for (int kt = 0; kt < KD / 64; ++kt) {
        __syncthreads();
#pragma unroll
        for (int i = 0; i < 4; ++i) {
            int seg = wid * 4 + i;
            int r = seg * 8 + lr;
            gld_lds16(smem + seg * 1024,
                      A + (size_t)(bm * 128 + r) * KD + kt * 64 + (lc ^ (r & 7)) * 8);
            gld_lds16(smem + 16384 + seg * 1024,
                      Bw + (size_t)(bn * 128 + r) * KD + kt * 64 + (lc ^ (r & 7)) * 8);
        }
        __syncthreads();
#pragma unroll
        for (int ks = 0; ks < 2; ++ks) {
            bf16x8 bfr[4];
#pragma unroll
            for (int nf = 0; nf < 4; ++nf) {
                int rb = wn * 64 + nf * 16 + lrow;
                bfr[nf] = *(bf16x8_ma*)(smem + 16384 + ((rb * 128 + ks * 64 + lgrp * 16) ^ ((rb & 7) << 4)));
            }
#pragma unroll
            for (int mf = 0; mf < 4; ++mf) {
                int ra = wm * 64 + mf * 16 + lrow;
                bf16x8 af = *(bf16x8_ma*)(smem + ((ra * 128 + ks * 64 + lgrp * 16) ^ ((ra & 7) << 4)));
#pragma unroll
                for (int nf = 0; nf < 4; ++nf)
                    acc[mf][nf] = __builtin_amdgcn_mfma_f32_16x16x32_bf16(af, bfr[nf], acc[mf][nf], 0, 0, 0);
            }
        }
    }

#pragma unroll
    for (int mf = 0; mf < 4; ++mf) {
#pragma unroll
        for (int nf = 0; nf < 4; ++nf) {
            int j0 = bn * 128 + wn * 64 + nf * 16 + lrow;
            int m0 = bm * 128 + wm * 64 + mf * 16 + lgrp * 4;
#pragma unroll
            for (int r = 0; r < 4; ++r)
                C[(size_t)(m0 + r) * KDIM + j0] = acc[mf][nf][r];
        }
    }
}

extern "C" void kernel_launch(void* const* d_in, const int* in_sizes, int n_in,
                              void* d_out, int out_size, void* d_ws, size_t ws_size,
                              hipStream_t stream)
{
    const float* x    = (const float*)d_in[0];
    const float* Wsq  = (const float*)d_in[1];
    const float* Wsk  = (const float*)d_in[2];
    const float* Wrv  = (const float*)d_in[3];
    const float* Wrq  = (const float*)d_in[4];
    const float* Wrk  = (const float*)d_in[5];
    const float* Wout = (const float*)d_in[6];
    float* out = (float*)d_out;

    // workspace layout (R19 layout)
    unsigned short* RUb  = (unsigned short*)d_ws;               // [16][2048][64] bf16, 4 MB
    unsigned short* Wt   = RUb + (size_t)2 * NS * NSEQ * DH;    // [1664][1024], 3.25 MB
    unsigned short* Wot  = Wt + (size_t)1664 * KDIM;            // [1024][512], 1 MB
    unsigned short* Qb   = Wot + (size_t)KDIM * 512;            // [16][2048][64], 4 MB
    unsigned short* Kfr  = Qb + (size_t)2 * NS * NSEQ * DH;     // fragmented K, 4 MB
    unsigned short* Vfr  = Kfr + (size_t)2 * NS * NSEQ * DH;    // fragmented V, 1 MB
    unsigned short* xh   = Vfr + (size_t)2 * 128 * NSEQ;        // [4096][1024], 8 MB
    unsigned short* O1b  = xh;  // alias: xh dead after proj_mfma_k

    prep_all_k<<<2720, 256, 0, stream>>>(Wsq, Wsk, Wrq, Wrv, Wout, Wrk, x, Wt, Wot, xh);
    proj_mfma_k<<<dim3(13, 32), 256, 0, stream>>>(xh, Wt, Qb, Kfr, RUb, Vfr);
    attn_mfma_k<<<512, 256, 0, stream>>>(Qb, Kfr, Vfr, RUb, O1b);
    out_mfma_k<<<dim3(8, 32), 256, 0, stream>>>(O1b, Wot, out);
}